// Round 1
// baseline (102.321 us; speedup 1.0000x reference)
//
#include <hip/hip_runtime.h>
#include <math.h>

#define H 256
#define W 256
#define TS 16

// Spiral rank LUT, indexed by (dy+3)*7 + (dx+3). Verified against the
// reference _spiral_rank() traversal (center-out, right/down/left/up).
__device__ __constant__ int SPIRAL_RANK[49] = {
    42,43,44,45,46,47,48,
    41,20,21,22,23,24,25,
    40,19, 6, 7, 8, 9,26,
    39,18, 5, 0, 1,10,27,
    38,17, 4, 3, 2,11,28,
    37,16,15,14,13,12,29,
    36,35,34,33,32,31,30
};

// Kernel 1: binomial blur (replicate pad) + quantize to uint8-valued.
// Computed as 3 vertical passes then horizontal combine -> bitwise identical
// to the reference's separable two-pass form.
__global__ void k_binq(const float* __restrict__ f, const float* __restrict__ g,
                       float* __restrict__ fb,
                       short* __restrict__ fq, short* __restrict__ gq) {
    int x = blockIdx.x * blockDim.x + threadIdx.x;
    int y = blockIdx.y * blockDim.y + threadIdx.y;
    if (x >= W || y >= H) return;
    int ym = max(y - 1, 0), yp = min(y + 1, H - 1);
    int xm = max(x - 1, 0), xp = min(x + 1, W - 1);

    float fvm = (f[ym*W+xm] + 2.0f*f[y*W+xm] + f[yp*W+xm]) * 0.25f;
    float fv0 = (f[ym*W+x ] + 2.0f*f[y*W+x ] + f[yp*W+x ]) * 0.25f;
    float fvp = (f[ym*W+xp] + 2.0f*f[y*W+xp] + f[yp*W+xp]) * 0.25f;
    float fbv = (fvm + 2.0f*fv0 + fvp) * 0.25f;

    float gvm = (g[ym*W+xm] + 2.0f*g[y*W+xm] + g[yp*W+xm]) * 0.25f;
    float gv0 = (g[ym*W+x ] + 2.0f*g[y*W+x ] + g[yp*W+x ]) * 0.25f;
    float gvp = (g[ym*W+xp] + 2.0f*g[y*W+xp] + g[yp*W+xp]) * 0.25f;
    float gbv = (gvm + 2.0f*gv0 + gvp) * 0.25f;

    fb[y*W+x] = fbv;
    float fqv = fminf(fmaxf(rintf(fbv * 255.0f), 0.0f), 255.0f);
    float gqv = fminf(fmaxf(rintf(gbv * 255.0f), 0.0f), 255.0f);
    fq[y*W+x] = (short)fqv;
    gq[y*W+x] = (short)gqv;
}

// Kernel 2: SAD block-matching search (7x7 window, 5x5 template, spiral
// tie-break) + fused Lucas-Kanade subpixel on the 16-tap border ring.
__global__ void k_search(const short* __restrict__ fq, const short* __restrict__ gq,
                         const float* __restrict__ fb, float* __restrict__ flow) {
    __shared__ short sfq[26][26];   // apron 5 (search 3 + template 2), zero pad
    __shared__ short sgq[20][20];   // apron 2, zero pad
    __shared__ float sfb[22][22];   // apron 3 (template 2 + gradient 1), replicate

    int tx = threadIdx.x, ty = threadIdx.y;
    int bx0 = blockIdx.x * TS, by0 = blockIdx.y * TS;
    int tid = ty * TS + tx;

    for (int i = tid; i < 26*26; i += 256) {
        int r = i / 26, c = i % 26;
        int gy = by0 + r - 5, gx = bx0 + c - 5;
        ((short*)sfq)[i] = (gy >= 0 && gy < H && gx >= 0 && gx < W) ? fq[gy*W+gx] : 0;
    }
    for (int i = tid; i < 20*20; i += 256) {
        int r = i / 20, c = i % 20;
        int gy = by0 + r - 2, gx = bx0 + c - 2;
        ((short*)sgq)[i] = (gy >= 0 && gy < H && gx >= 0 && gx < W) ? gq[gy*W+gx] : 0;
    }
    for (int i = tid; i < 22*22; i += 256) {
        int r = i / 22, c = i % 22;
        int gy = min(max(by0 + r - 3, 0), H - 1);
        int gx = min(max(bx0 + c - 3, 0), W - 1);
        ((float*)sfb)[i] = fb[gy*W+gx];
    }
    __syncthreads();

    int x = bx0 + tx, y = by0 + ty;

    // g template (zero-padded 5x5 around this pixel) into registers
    int gt[25];
    #pragma unroll
    for (int kh = 0; kh < 5; kh++)
        #pragma unroll
        for (int kw = 0; kw < 5; kw++)
            gt[kh*5+kw] = sgq[ty+kh][tx+kw];

    int best = 0x7fffffff, bestd = 0;
    for (int sj = 0; sj < 7; sj++) {
        for (int si = 0; si < 7; si++) {
            int sad = 0;
            #pragma unroll
            for (int kh = 0; kh < 5; kh++)
                #pragma unroll
                for (int kw = 0; kw < 5; kw++)
                    sad += abs((int)sfq[ty+sj+kh][tx+si+kw] - gt[kh*5+kw]);
            int score = sad * 64 + SPIRAL_RANK[sj*7+si];
            if (score < best) { best = score; bestd = sj*7+si; }
        }
    }
    int dy = bestd / 7 - 3, dx = bestd % 7 - 3;

    // Subpixel: only the 16 ring taps contribute (pred mask). OOB taps
    // contribute nothing because the zero-padded gradient template factor
    // multiplies every accumulated term.
    float a = 0.f, b = 0.f, d = 0.f, p = 0.f, q = 0.f;
    #pragma unroll
    for (int kh = 0; kh < 5; kh++) {
        #pragma unroll
        for (int kw = 0; kw < 5; kw++) {
            if (kh != 0 && kh != 4 && kw != 0 && kw != 4) continue;  // ring only
            int yy = y + kh - 2, xx = x + kw - 2;
            if (yy < 0 || yy >= H || xx < 0 || xx >= W) continue;
            int ry = ty + kh + 1, rx = tx + kw + 1;   // (yy,xx) in sfb coords
            float gxv = (sfb[ry][rx+1] - sfb[ry][rx-1]) * 0.5f;
            float gyv = (sfb[ry+1][rx] - sfb[ry-1][rx]) * 0.5f;
            float fv = (float)sfq[ty + dy + kh + 3][tx + dx + kw + 3] / 255.0f;
            float gv = (float)gt[kh*5+kw] / 255.0f;
            float z = gv - fv;
            a += gxv * gxv;
            b += gxv * gyv;
            d += gyv * gyv;
            p += z * gxv;
            q += z * gyv;
        }
    }
    float det = a * d - b * b;
    float u = d * p - b * q;     // x
    float v = a * q - b * p;     // y
    float suby = 0.f, subx = 0.f;
    if (det > 1e-7f) {
        suby = v / det;
        subx = u / det;
        if (fabsf(suby) >= 1.0f) suby = 0.f;
        if (fabsf(subx) >= 1.0f) subx = 0.f;
    }
    flow[y*W + x]         = (float)(-dy) + suby;
    flow[H*W + y*W + x]   = (float)(-dx) + subx;
}

// Kernel 3: 3x3 median, replicate padding, per channel.
__global__ void k_median(const float* __restrict__ in, float* __restrict__ out) {
    int x = blockIdx.x * blockDim.x + threadIdx.x;
    int y = blockIdx.y * blockDim.y + threadIdx.y;
    int c = blockIdx.z;
    if (x >= W || y >= H) return;
    const float* pl = in + c * H * W;
    float v[9];
    int n = 0;
    #pragma unroll
    for (int j = -1; j <= 1; j++)
        #pragma unroll
        for (int i = -1; i <= 1; i++) {
            int yy = min(max(y + j, 0), H - 1);
            int xx = min(max(x + i, 0), W - 1);
            v[n++] = pl[yy*W + xx];
        }
#define MSWAP(a, b) { float t_ = fminf(v[a], v[b]); v[b] = fmaxf(v[a], v[b]); v[a] = t_; }
    MSWAP(1,2); MSWAP(4,5); MSWAP(7,8);
    MSWAP(0,1); MSWAP(3,4); MSWAP(6,7);
    MSWAP(1,2); MSWAP(4,5); MSWAP(7,8);
    MSWAP(0,3); MSWAP(5,8); MSWAP(4,7);
    MSWAP(3,6); MSWAP(1,4); MSWAP(2,5);
    MSWAP(4,7); MSWAP(4,2); MSWAP(6,4);
    MSWAP(4,2);
#undef MSWAP
    out[c*H*W + y*W + x] = v[4];
}

// Kernel 4: bilateral (5x5, zero-padded patches, constant spatial kernel).
__global__ void k_bilateral(const float* __restrict__ fb, const float* __restrict__ vec,
                            float* __restrict__ out) {
    int x = blockIdx.x * blockDim.x + threadIdx.x;
    int y = blockIdx.y * blockDim.y + threadIdx.y;
    if (x >= W || y >= H) return;
    const float kern = -0.22222222222222221f;   // -1/(2*1.5^2)
    const float sii  = 200.0f;                  // 1/(2*0.05^2) rounded to f32
    float cp = fb[y*W + x];
    float sc = 0.f, sy = 0.f, sx = 0.f;
    #pragma unroll
    for (int j = -2; j <= 2; j++) {
        #pragma unroll
        for (int i = -2; i <= 2; i++) {
            int yy = y + j, xx = x + i;
            bool inb = (yy >= 0 && yy < H && xx >= 0 && xx < W);
            float ck = inb ? fb[yy*W + xx] : 0.0f;
            float df = cp - ck;
            float idiff = df * df;
            float coeff = 1.0f - fabsf(kern - idiff * sii);
            coeff = fminf(fmaxf(coeff, 0.0f), 1.0f);
            sc += coeff;
            sy += coeff * (inb ? vec[yy*W + xx] : 0.0f);
            sx += coeff * (inb ? vec[H*W + yy*W + xx] : 0.0f);
        }
    }
    out[y*W + x]       = sy / sc;
    out[H*W + y*W + x] = sx / sc;
}

extern "C" void kernel_launch(void* const* d_in, const int* in_sizes, int n_in,
                              void* d_out, int out_size, void* d_ws, size_t ws_size,
                              hipStream_t stream) {
    const float* f = (const float*)d_in[0];
    const float* g = (const float*)d_in[1];
    float* out = (float*)d_out;

    char* ws = (char*)d_ws;
    float* fb    = (float*)(ws);                       // 256 KiB
    short* fq    = (short*)(ws + 262144);              // 128 KiB
    short* gq    = (short*)(ws + 262144 + 131072);     // 128 KiB
    float* flow1 = (float*)(ws + 524288);              // 512 KiB
    float* flow2 = (float*)(ws + 1048576);             // 512 KiB

    dim3 blk(TS, TS);
    dim3 grd(W / TS, H / TS);
    k_binq     <<<grd, blk, 0, stream>>>(f, g, fb, fq, gq);
    k_search   <<<grd, blk, 0, stream>>>(fq, gq, fb, flow1);
    k_median   <<<dim3(W / TS, H / TS, 2), blk, 0, stream>>>(flow1, flow2);
    k_bilateral<<<grd, blk, 0, stream>>>(fb, flow2, out);
}

// Round 2
// 67.984 us; speedup vs baseline: 1.5051x; 1.5051x over previous
//
#include <hip/hip_runtime.h>
#include <math.h>

#define H 256
#define W 256
#define TS 16

#if __has_builtin(__builtin_amdgcn_alignbyte)
__device__ __forceinline__ unsigned align_b(unsigned hi, unsigned lo, int sh) {
    return __builtin_amdgcn_alignbyte(hi, lo, sh);
}
#else
__device__ __forceinline__ unsigned align_b(unsigned hi, unsigned lo, int sh) {
    unsigned d;
    asm("v_alignbyte_b32 %0, %1, %2, %3" : "=v"(d) : "v"(hi), "v"(lo), "v"(sh));
    return d;
}
#endif

#if __has_builtin(__builtin_amdgcn_sad_u8)
__device__ __forceinline__ unsigned sad_u8(unsigned a, unsigned b, unsigned acc) {
    return __builtin_amdgcn_sad_u8(a, b, acc);
}
#else
__device__ __forceinline__ unsigned sad_u8(unsigned a, unsigned b, unsigned acc) {
    unsigned d;
    asm("v_sad_u8 %0, %1, %2, %3" : "=v"(d) : "v"(a), "v"(b), "v"(acc));
    return d;
}
#endif

// Kernel 1: binomial blur (replicate pad) + quantize to uint8.
__global__ void k_binq(const float* __restrict__ f, const float* __restrict__ g,
                       float* __restrict__ fb,
                       unsigned char* __restrict__ fq, unsigned char* __restrict__ gq) {
    int x = blockIdx.x * blockDim.x + threadIdx.x;
    int y = blockIdx.y * blockDim.y + threadIdx.y;
    if (x >= W || y >= H) return;
    int ym = max(y - 1, 0), yp = min(y + 1, H - 1);
    int xm = max(x - 1, 0), xp = min(x + 1, W - 1);

    float fvm = (f[ym*W+xm] + 2.0f*f[y*W+xm] + f[yp*W+xm]) * 0.25f;
    float fv0 = (f[ym*W+x ] + 2.0f*f[y*W+x ] + f[yp*W+x ]) * 0.25f;
    float fvp = (f[ym*W+xp] + 2.0f*f[y*W+xp] + f[yp*W+xp]) * 0.25f;
    float fbv = (fvm + 2.0f*fv0 + fvp) * 0.25f;

    float gvm = (g[ym*W+xm] + 2.0f*g[y*W+xm] + g[yp*W+xm]) * 0.25f;
    float gv0 = (g[ym*W+x ] + 2.0f*g[y*W+x ] + g[yp*W+x ]) * 0.25f;
    float gvp = (g[ym*W+xp] + 2.0f*g[y*W+xp] + g[yp*W+xp]) * 0.25f;
    float gbv = (gvm + 2.0f*gv0 + gvp) * 0.25f;

    fb[y*W+x] = fbv;
    fq[y*W+x] = (unsigned char)fminf(fmaxf(rintf(fbv * 255.0f), 0.0f), 255.0f);
    gq[y*W+x] = (unsigned char)fminf(fmaxf(rintf(gbv * 255.0f), 0.0f), 255.0f);
}

// Kernel 2: packed-byte SAD search (v_sad_u8, register-resident window)
// + fused Lucas-Kanade subpixel on the 16-tap template ring.
__global__ void __launch_bounds__(256)
k_search(const unsigned char* __restrict__ fq, const unsigned char* __restrict__ gq,
         const float* __restrict__ fb, float* __restrict__ flow) {
    // fq region: rows/cols [-5, +20] -> 26 rows, 28 byte cols (7 dwords)
    // gq region: rows/cols [-2, +17] -> 20 rows, 20 byte cols (5 dwords)
    // fb region: [-3, +18] -> 22x22 floats (replicate pad)
    __shared__ unsigned sfq[26 * 7];
    __shared__ unsigned sgq[20 * 5];
    __shared__ float    sfb[22 * 22];

    int tx = threadIdx.x, ty = threadIdx.y;
    int bx0 = blockIdx.x * TS, by0 = blockIdx.y * TS;
    int tid = ty * TS + tx;

    unsigned char* sfq_b = (unsigned char*)sfq;
    unsigned char* sgq_b = (unsigned char*)sgq;

    for (int i = tid; i < 26 * 28; i += 256) {
        int r = i / 28, c = i % 28;
        int gy = by0 + r - 5, gx = bx0 + c - 5;
        sfq_b[i] = (gy >= 0 && gy < H && gx >= 0 && gx < W) ? fq[gy*W+gx] : 0;
    }
    for (int i = tid; i < 20 * 20; i += 256) {
        int r = i / 20, c = i % 20;
        int gy = by0 + r - 2, gx = bx0 + c - 2;
        sgq_b[r * 20 + c] = (gy >= 0 && gy < H && gx >= 0 && gx < W) ? gq[gy*W+gx] : 0;
    }
    for (int i = tid; i < 22 * 22; i += 256) {
        int r = i / 22, c = i % 22;
        int gy = min(max(by0 + r - 3, 0), H - 1);
        int gx = min(max(bx0 + c - 3, 0), W - 1);
        sfb[i] = fb[gy*W+gx];
    }
    __syncthreads();

    int x = bx0 + tx, y = by0 + ty;
    int base = tx >> 2, a = tx & 3;

    // Per-thread fq window: bytes [x-5 .. x+6] for rows [y-5 .. y+5],
    // normalized so byte j of w[r] = fq[y-5+r][x-5+j].
    unsigned w0[11], w1[11], w2[11];
    #pragma unroll
    for (int r = 0; r < 11; r++) {
        const unsigned* row = &sfq[(ty + r) * 7 + base];
        unsigned d0 = row[0], d1 = row[1], d2 = row[2], d3 = row[3];
        w0[r] = align_b(d1, d0, a);
        w1[r] = align_b(d2, d1, a);
        w2[r] = align_b(d3, d2, a);
    }

    // g template: row kh -> gq[y-2+kh][x-2 .. x+2]: 4 bytes + 1 byte
    unsigned gt_lo[5], gt_hi[5];
    #pragma unroll
    for (int r = 0; r < 5; r++) {
        const unsigned* row = &sgq[(ty + r) * 5 + base];
        unsigned d0 = row[0], d1 = row[1];
        gt_lo[r] = align_b(d1, d0, a);
        gt_hi[r] = (d1 >> (8 * a)) & 0xFFu;
    }

    // Spiral rank, indexed (dy+3)*7+(dx+3); folds to immediates (full unroll).
    const unsigned RANKC[49] = {
        42,43,44,45,46,47,48,
        41,20,21,22,23,24,25,
        40,19, 6, 7, 8, 9,26,
        39,18, 5, 0, 1,10,27,
        38,17, 4, 3, 2,11,28,
        37,16,15,14,13,12,29,
        36,35,34,33,32,31,30
    };

    unsigned best = 0xFFFFFFFFu;
    int bestd = 0;
    #pragma unroll
    for (int si = 0; si < 7; si++) {
        // window bytes si..si+3 and si+4 for all 11 rows (hoisted per si)
        unsigned fd[11], f5[11];
        #pragma unroll
        for (int r = 0; r < 11; r++) {
            fd[r] = (si < 4) ? align_b(w1[r], w0[r], si) : align_b(w2[r], w1[r], si - 4);
            f5[r] = (si < 4) ? ((w1[r] >> (8 * si)) & 0xFFu)
                             : ((w2[r] >> (8 * (si - 4))) & 0xFFu);
        }
        #pragma unroll
        for (int sj = 0; sj < 7; sj++) {
            unsigned acc0 = 0, acc1 = 0;
            #pragma unroll
            for (int kh = 0; kh < 5; kh++) {
                acc0 = sad_u8(fd[sj + kh], gt_lo[kh], acc0);
                acc1 = sad_u8(f5[sj + kh], gt_hi[kh], acc1);
            }
            unsigned score = ((acc0 + acc1) << 6) + RANKC[sj * 7 + si];
            if (score < best) { best = score; bestd = sj * 7 + si; }
        }
    }
    int dy = bestd / 7 - 3, dx = bestd % 7 - 3;

    // Subpixel: 16-tap border ring; OOB taps contribute nothing (gradient
    // factor multiplies every term and comes from the zero-measure region).
    float aA = 0.f, bB = 0.f, dD = 0.f, pP = 0.f, qQ = 0.f;
    #pragma unroll
    for (int kh = 0; kh < 5; kh++) {
        #pragma unroll
        for (int kw = 0; kw < 5; kw++) {
            if (kh != 0 && kh != 4 && kw != 0 && kw != 4) continue;  // ring only
            int yy = y + kh - 2, xx = x + kw - 2;
            if (yy < 0 || yy >= H || xx < 0 || xx >= W) continue;
            int ry = ty + kh + 1, rx = tx + kw + 1;   // sfb coords
            float gxv = (sfb[ry*22 + rx+1] - sfb[ry*22 + rx-1]) * 0.5f;
            float gyv = (sfb[(ry+1)*22 + rx] - sfb[(ry-1)*22 + rx]) * 0.5f;
            float fv = (float)sfq_b[(ty + dy + kh + 3) * 28 + (tx + dx + kw + 3)] * (1.0f/255.0f);
            float gv = (float)((kw < 4) ? ((gt_lo[kh] >> (8*kw)) & 0xFFu) : gt_hi[kh]) * (1.0f/255.0f);
            float z = gv - fv;
            aA += gxv * gxv;
            bB += gxv * gyv;
            dD += gyv * gyv;
            pP += z * gxv;
            qQ += z * gyv;
        }
    }
    float det = aA * dD - bB * bB;
    float u = dD * pP - bB * qQ;     // x
    float v = aA * qQ - bB * pP;     // y
    float suby = 0.f, subx = 0.f;
    if (det > 1e-7f) {
        suby = v / det;
        subx = u / det;
        if (fabsf(suby) >= 1.0f) suby = 0.f;
        if (fabsf(subx) >= 1.0f) subx = 0.f;
    }
    flow[y*W + x]       = (float)(-dy) + suby;
    flow[H*W + y*W + x] = (float)(-dx) + subx;
}

// Kernel 3: fused 3x3 median (replicate pad) + 5x5 bilateral (zero pad),
// with halo recompute of the median in LDS.
__global__ void __launch_bounds__(256)
k_medbil(const float* __restrict__ flow1, const float* __restrict__ fb,
         float* __restrict__ out) {
    __shared__ float sfl[2][22 * 22];   // flow1, image-replicate-clamped, tile+3
    __shared__ float smed[2][20 * 20];  // median result, 0 for OOB, tile+2
    __shared__ float sfbt[20 * 20];     // fb, 0 for OOB, tile+2

    int tx = threadIdx.x, ty = threadIdx.y;
    int bx0 = blockIdx.x * TS, by0 = blockIdx.y * TS;
    int tid = ty * TS + tx;

    for (int i = tid; i < 2 * 22 * 22; i += 256) {
        int c = i / 484, rem = i % 484;
        int r = rem / 22, col = rem % 22;
        int qy = min(max(by0 + r - 3, 0), H - 1);
        int qx = min(max(bx0 + col - 3, 0), W - 1);
        sfl[c][rem] = flow1[c*H*W + qy*W + qx];
    }
    for (int i = tid; i < 20 * 20; i += 256) {
        int r = i / 20, col = i % 20;
        int yy = by0 + r - 2, xx = bx0 + col - 2;
        sfbt[i] = (yy >= 0 && yy < H && xx >= 0 && xx < W) ? fb[yy*W+xx] : 0.0f;
    }
    __syncthreads();

    for (int i = tid; i < 2 * 20 * 20; i += 256) {
        int c = i / 400, rem = i % 400;
        int r = rem / 20, col = rem % 20;
        int py = by0 + r - 2, px = bx0 + col - 2;
        float m = 0.0f;
        if (py >= 0 && py < H && px >= 0 && px < W) {
            float v[9];
            int n = 0;
            #pragma unroll
            for (int j = 0; j < 3; j++)
                #pragma unroll
                for (int ii = 0; ii < 3; ii++)
                    v[n++] = sfl[c][(r + j) * 22 + (col + ii)];
#define MSWAP(A, B) { float t_ = fminf(v[A], v[B]); v[B] = fmaxf(v[A], v[B]); v[A] = t_; }
            MSWAP(1,2); MSWAP(4,5); MSWAP(7,8);
            MSWAP(0,1); MSWAP(3,4); MSWAP(6,7);
            MSWAP(1,2); MSWAP(4,5); MSWAP(7,8);
            MSWAP(0,3); MSWAP(5,8); MSWAP(4,7);
            MSWAP(3,6); MSWAP(1,4); MSWAP(2,5);
            MSWAP(4,7); MSWAP(4,2); MSWAP(6,4);
            MSWAP(4,2);
#undef MSWAP
            m = v[4];
        }
        smed[c][rem] = m;
    }
    __syncthreads();

    int x = bx0 + tx, y = by0 + ty;
    const float kern = -0.22222222222222221f;   // -1/(2*1.5^2)
    const float sii  = 200.0f;                  // 1/(2*0.05^2)
    float cp = sfbt[(ty + 2) * 20 + (tx + 2)];
    float sc = 0.f, sy = 0.f, sx = 0.f;
    #pragma unroll
    for (int j = 0; j < 5; j++) {
        #pragma unroll
        for (int i = 0; i < 5; i++) {
            int s = (ty + j) * 20 + (tx + i);
            float ck = sfbt[s];
            float df = cp - ck;
            float coeff = 1.0f - fabsf(kern - df * df * sii);
            coeff = fminf(fmaxf(coeff, 0.0f), 1.0f);
            sc += coeff;
            sy += coeff * smed[0][s];
            sx += coeff * smed[1][s];
        }
    }
    out[y*W + x]       = sy / sc;
    out[H*W + y*W + x] = sx / sc;
}

extern "C" void kernel_launch(void* const* d_in, const int* in_sizes, int n_in,
                              void* d_out, int out_size, void* d_ws, size_t ws_size,
                              hipStream_t stream) {
    const float* f = (const float*)d_in[0];
    const float* g = (const float*)d_in[1];
    float* out = (float*)d_out;

    char* ws = (char*)d_ws;
    float*         fb    = (float*)(ws);                    // 256 KiB
    unsigned char* fq    = (unsigned char*)(ws + 262144);   //  64 KiB
    unsigned char* gq    = (unsigned char*)(ws + 327680);   //  64 KiB
    float*         flow1 = (float*)(ws + 393216);           // 512 KiB

    dim3 blk(TS, TS);
    dim3 grd(W / TS, H / TS);
    k_binq  <<<grd, blk, 0, stream>>>(f, g, fb, fq, gq);
    k_search<<<grd, blk, 0, stream>>>(fq, gq, fb, flow1);
    k_medbil<<<grd, blk, 0, stream>>>(flow1, fb, out);
}